// Round 7
// baseline (383.066 us; speedup 1.0000x reference)
//
#include <hip/hip_runtime.h>
#include <hip/hip_bf16.h>
#include <math.h>

// Problem constants (B=2,S=1024 -> T=2048; D=1024; H=4096; E=8; top-2)
#define NTOK 2048
#define DDIM 1024
#define HDIM 4096
#define NEXP 8
#define NROWS (3 * NTOK)
#define KSPLIT2 4   // split-K for GEMM2: 1536 active blocks = 6/CU backlog

typedef __bf16 bf16x8 __attribute__((ext_vector_type(8)));
typedef float f32x4 __attribute__((ext_vector_type(4)));
typedef __attribute__((address_space(1))) char as1_char;
typedef __attribute__((address_space(3))) char as3_char;

__device__ __forceinline__ void async16(const void* g, void* l) {
  __builtin_amdgcn_global_load_lds((as1_char*)g, (as3_char*)l, 16, 0, 0);
}

// Branch-free erf (A-S 7.1.26) -> exact-form gelu.
__device__ __forceinline__ float gelu_fast(float v) {
  const float x = v * 0.70710678118654752f;
  const float ax = fabsf(x);
  const float t = __builtin_amdgcn_rcpf(1.0f + 0.3275911f * ax);
  float p = 1.061405429f;
  p = p * t - 1.453152027f;
  p = p * t + 1.421413741f;
  p = p * t - 0.284496736f;
  p = p * t + 0.254829592f;
  const float y = 1.0f - p * t * __expf(-ax * ax);
  const float erfv = copysignf(y, x);
  return 0.5f * v * (1.0f + erfv);
}

// ---------------------------------------------------------------------------
// Fused f32->bf16 conversion for ALL five tensors in ONE launch (+ counts
// zeroing in block 0). Segment sizes are multiples of 2048 elems.
// Block ranges: x 1024 | W1 16384 | W2 16384 | Ws1 2048 | Ws2 2048 = 37888.
// ---------------------------------------------------------------------------
__global__ void __launch_bounds__(256) cvt_all(
    const float* __restrict__ x, const float* __restrict__ W1,
    const float* __restrict__ W2, const float* __restrict__ Ws1,
    const float* __restrict__ Ws2, __hip_bfloat16* __restrict__ xbf,
    __hip_bfloat16* __restrict__ W1bf, __hip_bfloat16* __restrict__ W2bf,
    __hip_bfloat16* __restrict__ Ws1bf, __hip_bfloat16* __restrict__ Ws2bf,
    int* __restrict__ counts) {
  const int b = blockIdx.x;
  if (b == 0 && threadIdx.x < NEXP) counts[threadIdx.x] = 0;
  const float* src;
  __hip_bfloat16* dst;
  size_t base;
  if (b < 1024)        { src = x;   dst = xbf;   base = (size_t)b * 2048; }
  else if (b < 17408)  { src = W1;  dst = W1bf;  base = (size_t)(b - 1024) * 2048; }
  else if (b < 33792)  { src = W2;  dst = W2bf;  base = (size_t)(b - 17408) * 2048; }
  else if (b < 35840)  { src = Ws1; dst = Ws1bf; base = (size_t)(b - 33792) * 2048; }
  else                 { src = Ws2; dst = Ws2bf; base = (size_t)(b - 35840) * 2048; }
  const size_t i = base + (size_t)threadIdx.x * 8;
  const float4 a = *(const float4*)(src + i);
  const float4 c = *(const float4*)(src + i + 4);
  union { __hip_bfloat16 h[8]; uint4 u; } p;
  p.h[0] = __float2bfloat16(a.x); p.h[1] = __float2bfloat16(a.y);
  p.h[2] = __float2bfloat16(a.z); p.h[3] = __float2bfloat16(a.w);
  p.h[4] = __float2bfloat16(c.x); p.h[5] = __float2bfloat16(c.y);
  p.h[6] = __float2bfloat16(c.z); p.h[7] = __float2bfloat16(c.w);
  *(uint4*)(dst + i) = p.u;
}

__global__ void moe_zero_out(float* __restrict__ a) {
  a[(size_t)blockIdx.x * 256 + threadIdx.x] = 0.f;
}

// ---------------------------------------------------------------------------
// Round-11 core: back to the PROVEN 128x128 / 4-wave / 2-buffer depth-1
// counted-vmcnt loop (round-1 schedule + round-2 bank-free swizzle,
// SQ_LDS_BANK_CONFLICT == 0 verified). LDS = 2 x 16KB = 32KB -> 5 blocks/CU
// resident (LDS 160/32; VGPR 76 x 5 waves/SIMD = 380 < 512).
// Post-mortem r0-r6: per-CU block-iter retire rate was ~1000-1200 cyc vs
// m97's 245 cyc on the IDENTICAL structure -- every pipe <=40%, occupancy
// never >22%. The kernels are LATENCY-bound on cold-HBM staging loads with
// too few resident waves. This round attacks residency (5 blocks/CU, 6/CU
// backlog via KSPLIT2=4) and source latency (XCD co-location of A-panel
// sharers, below) instead of the schedule.
// Schedule correctness (round-0/1 proven): stage(i+1) overwrites buf cur^1
// whose readers passed the trailing barrier of iter i-1; vmcnt(4) before the
// leading barrier waits only the current buffer's 4 DMAs (prefetch stays in
// flight across the barrier); the barrier publishes them to all 4 waves.
// ---------------------------------------------------------------------------
__device__ __forceinline__ void gemm_core(const char* ga0, const char* ga1,
                                          const char* gb0, const char* gb1,
                                          char* sm, int Kbytes, int tid,
                                          f32x4 acc[4][4]) {
  const int w = tid >> 6, l = tid & 63;
  const int lr = l & 15, quad = l >> 4;
  const int wr = w >> 1, wc = w & 1;
  const int swz = (lr >> 1) & 3;  // row-derived slot XOR (rows == lr mod 16)
  const int aoff = (wr * 64 + lr) * 64 + ((quad ^ swz) * 16);
  const int boff = 8192 + (wc * 64 + lr) * 64 + ((quad ^ swz) * 16);
  const int niter = Kbytes >> 6;

  auto stage = [&](int it, int buf) {
    char* base = sm + buf * 16384 + w * 1024;
    const int kb = it * 64;
    async16(ga0 + kb, base);
    async16(ga1 + kb, base + 4096);
    async16(gb0 + kb, base + 8192);
    async16(gb1 + kb, base + 12288);
  };

  stage(0, 0);
  for (int i = 0; i < niter; ++i) {
    const int cur = i & 1;
    if (i + 1 < niter) {
      stage(i + 1, cur ^ 1);                  // 8 DMAs outstanding (own)
      __builtin_amdgcn_s_waitcnt(0x0F74);     // vmcnt(4): wait stage(i) only
    } else {
      __builtin_amdgcn_s_waitcnt(0x0F70);     // vmcnt(0): last tile
    }
    __builtin_amdgcn_s_barrier();             // raw: prefetch stays in flight
    const char* rb = sm + cur * 16384;
    bf16x8 av[4], bv[4];
#pragma unroll
    for (int i2 = 0; i2 < 4; ++i2) av[i2] = *(const bf16x8*)(rb + aoff + i2 * 1024);
#pragma unroll
    for (int j = 0; j < 4; ++j) bv[j] = *(const bf16x8*)(rb + boff + j * 1024);
#pragma unroll
    for (int i2 = 0; i2 < 4; ++i2)
#pragma unroll
      for (int j = 0; j < 4; ++j)
        acc[i2][j] = __builtin_amdgcn_mfma_f32_16x16x32_bf16(av[i2], bv[j], acc[i2][j], 0, 0, 0);
    __builtin_amdgcn_s_barrier();             // all reads of buf[cur] done
  }
}

// lane l stages chunk ((l&3)^((l>>3)&3)) of row (l>>2) in each 16-row DMA:
// places chunk c of row r at slot c^((r>>1)&3) with a LINEAR LDS dest.
// Verified bank-free (round 2: SQ_LDS_BANK_CONFLICT 6.68M -> 0).
__device__ __forceinline__ int stage_colb(int l) {
  return (((l & 3) ^ ((l >> 3) & 3)) * 16);
}

// XCD group-swizzle decode: hardware block id hw = (g%8) + 8*member +
// 64*(g/8), bijective for grids of 4608 = 576 groups x 8 members. All 8
// members of a group share hw % 8 == g % 8 -> same XCD under round-robin
// dispatch, and are dispatched within 64 ids of each other (temporal
// locality). Members = the 8 blocks sharing one A-panel -> the panel is
// fetched ~once per XCD-L2 instead of 8x from HBM.
__device__ __forceinline__ void xcd_decode(int hw, int& g, int& m) {
  m = (hw >> 3) & 7;
  g = (hw & 7) + 8 * (hw >> 6);
}

// ---------------------------------------------------------------------------
// Gating: one wave per token. Top-2, lax.top_k tie-break (lowest index).
// ---------------------------------------------------------------------------
__global__ void __launch_bounds__(64) moe_gate(
    const float* __restrict__ x, const float* __restrict__ Wg,
    const float* __restrict__ bg, const float* __restrict__ bias,
    int* __restrict__ counts, int* __restrict__ topk_idx,
    float* __restrict__ topk_w, int* __restrict__ slot) {
  const int t = blockIdx.x, lane = threadIdx.x;
  float xv[16];
#pragma unroll
  for (int q = 0; q < 16; ++q) xv[q] = x[(size_t)t * DDIM + q * 64 + lane];
  float sc[NEXP];
#pragma unroll
  for (int e = 0; e < NEXP; ++e) {
    float s = 0.f;
#pragma unroll
    for (int q = 0; q < 16; ++q) s += xv[q] * Wg[(size_t)e * DDIM + q * 64 + lane];
#pragma unroll
    for (int o = 32; o > 0; o >>= 1) s += __shfl_xor(s, o, 64);
    sc[e] = 1.0f / (1.0f + expf(-(s + bg[e] + bias[e])));
  }
  if (lane == 0) {
    int k0 = 0;
    for (int e = 1; e < NEXP; ++e)
      if (sc[e] > sc[k0]) k0 = e;
    int k1 = (k0 == 0) ? 1 : 0;
    for (int e = 0; e < NEXP; ++e) {
      if (e == k0) continue;
      if (sc[e] > sc[k1]) k1 = e;
    }
    topk_idx[t * 2 + 0] = k0;
    topk_idx[t * 2 + 1] = k1;
    topk_w[t * 2 + 0] = sc[k0];
    topk_w[t * 2 + 1] = sc[k1];
    slot[t * 2 + 0] = atomicAdd(&counts[k0], 1);
    slot[t * 2 + 1] = atomicAdd(&counts[k1], 1);
  }
}

__global__ void moe_scan(const int* __restrict__ counts, int* __restrict__ offsets) {
  if (threadIdx.x == 0) {
    int s = 0;
    for (int e = 0; e < NEXP; ++e) { offsets[e] = s; s += counts[e]; }
    offsets[NEXP] = s;
  }
}

__global__ void moe_scatter(const int* __restrict__ topk_idx, const float* __restrict__ topk_w,
                            const int* __restrict__ slot, const int* __restrict__ offsets,
                            int* __restrict__ row_token, float* __restrict__ row_w) {
  const int t = blockIdx.x * blockDim.x + threadIdx.x;
  if (t >= NTOK) return;
#pragma unroll
  for (int k = 0; k < 2; ++k) {
    const int e = topk_idx[t * 2 + k];
    const int rg = offsets[e] + slot[t * 2 + k];
    row_token[rg] = t;
    row_w[rg] = topk_w[t * 2 + k];
  }
  row_token[2 * NTOK + t] = t;
  row_w[2 * NTOK + t] = 1.0f;
}

// ---------------------------------------------------------------------------
// Grouped GEMM1: h1[row,:] = gelu(xbf[token(row),:] @ W1bf[e]^T + b1[e])
// 128x128 tiles, 1-D grid 4608 with XCD group-swizzle:
// member m = nt&7; group g = (nt>>3) + 4*(mt + 16*e).
// ---------------------------------------------------------------------------
__global__ void __launch_bounds__(256) moe_gemm1(
    const __hip_bfloat16* __restrict__ xbf, const __hip_bfloat16* __restrict__ W1bf,
    const float* __restrict__ b1, const __hip_bfloat16* __restrict__ Ws1bf,
    const float* __restrict__ bs1, const int* __restrict__ counts,
    const int* __restrict__ offsets, const int* __restrict__ row_token,
    __hip_bfloat16* __restrict__ h1) {
  __shared__ alignas(16) char sm[32768];
  int g, m;
  xcd_decode(blockIdx.x, g, m);
  const int nt = m + 8 * (g & 3);
  const int mt = (g >> 2) & 15;
  const int e = g >> 6;
  const int cnt = (e < NEXP) ? counts[e] : NTOK;
  if (mt * 128 >= cnt) return;
  const int off = (e < NEXP) ? offsets[e] : 2 * NTOK;
  const __hip_bfloat16* Bw = (e < NEXP) ? (W1bf + (size_t)e * HDIM * DDIM) : Ws1bf;
  const float* bb = (e < NEXP) ? (b1 + e * HDIM) : bs1;

  const int tid = threadIdx.x;
  const int w = tid >> 6, l = tid & 63;
  const int mrow = w * 16 + (l >> 2);   // 0..63 staging row
  const int colb = stage_colb(l);       // swizzled 16B chunk col offset

  const int r0 = mt * 128 + mrow, r1 = r0 + 64;
  const int c0 = (r0 < cnt) ? r0 : (cnt - 1);
  const int c1 = (r1 < cnt) ? r1 : (cnt - 1);
  const int t0 = row_token[off + c0];
  const int t1 = row_token[off + c1];
  const char* ga0 = (const char*)xbf + (size_t)t0 * (DDIM * 2) + colb;
  const char* ga1 = (const char*)xbf + (size_t)t1 * (DDIM * 2) + colb;
  const char* gb0 = (const char*)Bw + (size_t)(nt * 128 + mrow) * (DDIM * 2) + colb;
  const char* gb1 = (const char*)Bw + (size_t)(nt * 128 + mrow + 64) * (DDIM * 2) + colb;

  f32x4 acc[4][4] = {};
  gemm_core(ga0, ga1, gb0, gb1, sm, DDIM * 2, tid, acc);

  const int lr = l & 15, quad = l >> 4, wr = w >> 1, wc = w & 1;
#pragma unroll
  for (int i = 0; i < 4; ++i) {
#pragma unroll
    for (int r = 0; r < 4; ++r) {
      const int rowe = mt * 128 + wr * 64 + i * 16 + quad * 4 + r;
      if (rowe >= cnt) continue;  // don't stomp next expert's rows
      const size_t orow = (size_t)(off + rowe) * HDIM;
#pragma unroll
      for (int j = 0; j < 4; ++j) {
        const int h = nt * 128 + wc * 64 + j * 16 + lr;
        const float v = acc[i][j][r] + bb[h];
        h1[orow + h] = __float2bfloat16(gelu_fast(v));
      }
    }
  }
}

// ---------------------------------------------------------------------------
// Grouped GEMM2 with split-K: out[token,:] += w(row)*(h1[row,:] @ W2bf[e]^T)
// (+ w*b2[e] from K-chunk 0). 128x128 tiles, 1-D grid 4608:
// member m = nt (the 8 sharers of one h1 A-panel -> one XCD);
// group g = kc + 4*(mt + 16*e). KB = HDIM*2/4 = 2048 B -> 32 iters.
// ---------------------------------------------------------------------------
__global__ void __launch_bounds__(256) moe_gemm2(
    const __hip_bfloat16* __restrict__ h1, const __hip_bfloat16* __restrict__ W2bf,
    const float* __restrict__ b2, const __hip_bfloat16* __restrict__ Ws2bf,
    const float* __restrict__ bs2, const int* __restrict__ counts,
    const int* __restrict__ offsets, const int* __restrict__ row_token,
    const float* __restrict__ row_w, float* __restrict__ out) {
  __shared__ alignas(16) char sm[32768];
  int g, m;
  xcd_decode(blockIdx.x, g, m);
  const int nt = m;                // 0..7 (D/128)
  const int kc = g & 3;            // 0..3 K-chunk
  const int mt = (g >> 2) & 15;
  const int e = g >> 6;
  const int cnt = (e < NEXP) ? counts[e] : NTOK;
  if (mt * 128 >= cnt) return;
  const int off = (e < NEXP) ? offsets[e] : 2 * NTOK;
  const __hip_bfloat16* Bw = (e < NEXP) ? (W2bf + (size_t)e * DDIM * HDIM) : Ws2bf;
  const float* bb = (e < NEXP) ? (b2 + e * DDIM) : bs2;

  const int tid = threadIdx.x;
  const int w = tid >> 6, l = tid & 63;
  const int mrow = w * 16 + (l >> 2);
  const int colb = stage_colb(l);
  const int KB = (HDIM * 2) / KSPLIT2;   // 2048 bytes per chunk
  const size_t kofs = (size_t)kc * KB;

  // A rows contiguous in grouped h1; rows >= cnt read the next group's valid
  // (finite) data and are discarded at the store guard.
  const char* ga0 = (const char*)h1 + (size_t)(off + mt * 128 + mrow) * (HDIM * 2) + kofs + colb;
  const char* ga1 = (const char*)h1 + (size_t)(off + mt * 128 + mrow + 64) * (HDIM * 2) + kofs + colb;
  const char* gb0 = (const char*)Bw + (size_t)(nt * 128 + mrow) * (HDIM * 2) + kofs + colb;
  const char* gb1 = (const char*)Bw + (size_t)(nt * 128 + mrow + 64) * (HDIM * 2) + kofs + colb;

  f32x4 acc[4][4] = {};
  gemm_core(ga0, ga1, gb0, gb1, sm, KB, tid, acc);

  const int lr = l & 15, quad = l >> 4, wr = w >> 1, wc = w & 1;
#pragma unroll
  for (int i = 0; i < 4; ++i) {
#pragma unroll
    for (int r = 0; r < 4; ++r) {
      const int rowe = mt * 128 + wr * 64 + i * 16 + quad * 4 + r;
      if (rowe >= cnt) continue;
      const int rg = off + rowe;
      const int tok = row_token[rg];
      const float wt = row_w[rg];
#pragma unroll
      for (int j = 0; j < 4; ++j) {
        const int d = nt * 128 + wc * 64 + j * 16 + lr;
        const float base = (kc == 0) ? bb[d] : 0.f;  // bias once per output
        atomicAdd(&out[(size_t)tok * DDIM + d], wt * (acc[i][j][r] + base));
      }
    }
  }
}

// ---------------------------------------------------------------------------
extern "C" void kernel_launch(void* const* d_in, const int* in_sizes, int n_in,
                              void* d_out, int out_size, void* d_ws, size_t ws_size,
                              hipStream_t stream) {
  (void)in_sizes; (void)n_in; (void)out_size; (void)ws_size;
  const float* x    = (const float*)d_in[0];
  const float* Wg   = (const float*)d_in[1];
  const float* bg   = (const float*)d_in[2];
  const float* bias = (const float*)d_in[3];
  const float* W1   = (const float*)d_in[4];
  const float* b1   = (const float*)d_in[5];
  const float* W2   = (const float*)d_in[6];
  const float* b2   = (const float*)d_in[7];
  const float* Ws1  = (const float*)d_in[8];
  const float* bs1  = (const float*)d_in[9];
  const float* Ws2  = (const float*)d_in[10];
  const float* bs2  = (const float*)d_in[11];
  float* out = (float*)d_out;

  char* ws = (char*)d_ws;
  size_t cur = 0;
  auto take = [&](size_t b) -> void* {
    void* p = ws + cur;
    cur += (b + 255) & ~(size_t)255;
    return p;
  };
  int* counts    = (int*)take(NEXP * 4);
  int* offsets   = (int*)take((NEXP + 1) * 4);
  int* topk_idx  = (int*)take(NTOK * 2 * 4);
  float* topk_w  = (float*)take(NTOK * 2 * 4);
  int* slot      = (int*)take(NTOK * 2 * 4);
  int* row_token = (int*)take(NROWS * 4);
  float* row_w   = (float*)take(NROWS * 4);
  __hip_bfloat16* xbf   = (__hip_bfloat16*)take((size_t)NTOK * DDIM * 2);
  __hip_bfloat16* W1bf  = (__hip_bfloat16*)take((size_t)NEXP * HDIM * DDIM * 2);
  __hip_bfloat16* W2bf  = (__hip_bfloat16*)take((size_t)NEXP * DDIM * HDIM * 2);
  __hip_bfloat16* Ws1bf = (__hip_bfloat16*)take((size_t)HDIM * DDIM * 2);
  __hip_bfloat16* Ws2bf = (__hip_bfloat16*)take((size_t)DDIM * HDIM * 2);
  __hip_bfloat16* h1    = (__hip_bfloat16*)take((size_t)(NROWS + 64) * HDIM * 2);

  // single fused f32->bf16 pass (x, W1, W2, Ws1, Ws2) + counts zeroing
  cvt_all<<<37888, 256, 0, stream>>>(x, W1, W2, Ws1, Ws2,
                                     xbf, W1bf, W2bf, Ws1bf, Ws2bf, counts);

  moe_zero_out<<<(NTOK * DDIM) / 256, 256, 0, stream>>>(out);
  moe_gate<<<NTOK, 64, 0, stream>>>(x, Wg, bg, bias, counts, topk_idx, topk_w, slot);
  moe_scan<<<1, 1, 0, stream>>>(counts, offsets);
  moe_scatter<<<NTOK / 256, 256, 0, stream>>>(topk_idx, topk_w, slot, offsets, row_token, row_w);

  // 1-D grids with in-kernel XCD group-swizzle decode:
  // gemm1: 32 nt x 16 mt x 9 e = 4608; gemm2: 8 nt x 4 kc x 16 mt x 9 e = 4608
  moe_gemm1<<<4608, 256, 0, stream>>>(xbf, W1bf, b1, Ws1bf, bs1, counts, offsets, row_token, h1);
  moe_gemm2<<<4608, 256, 0, stream>>>(h1, W2bf, b2, Ws2bf, bs2, counts, offsets, row_token, row_w, out);
}

// Round 8
// 362.722 us; speedup vs baseline: 1.0561x; 1.0561x over previous
//
#include <hip/hip_runtime.h>
#include <hip/hip_bf16.h>
#include <math.h>

// Problem constants (B=2,S=1024 -> T=2048; D=1024; H=4096; E=8; top-2)
#define NTOK 2048
#define DDIM 1024
#define HDIM 4096
#define NEXP 8
#define NROWS (3 * NTOK)
#define KSPLIT2 2

typedef __bf16 bf16x8 __attribute__((ext_vector_type(8)));
typedef float f32x4 __attribute__((ext_vector_type(4)));
typedef __attribute__((address_space(1))) char as1_char;
typedef __attribute__((address_space(3))) char as3_char;

__device__ __forceinline__ void async16(const void* g, void* l) {
  __builtin_amdgcn_global_load_lds((as1_char*)g, (as3_char*)l, 16, 0, 0);
}

// Branch-free erf (A-S 7.1.26) -> exact-form gelu.
__device__ __forceinline__ float gelu_fast(float v) {
  const float x = v * 0.70710678118654752f;
  const float ax = fabsf(x);
  const float t = __builtin_amdgcn_rcpf(1.0f + 0.3275911f * ax);
  float p = 1.061405429f;
  p = p * t - 1.453152027f;
  p = p * t + 1.421413741f;
  p = p * t - 0.284496736f;
  p = p * t + 0.254829592f;
  const float y = 1.0f - p * t * __expf(-ax * ax);
  const float erfv = copysignf(y, x);
  return 0.5f * v * (1.0f + erfv);
}

// ---------------------------------------------------------------------------
// f32 -> bf16 conversion for x ONLY (8 MB read) + counts zeroing in block 0.
// Round-8 change: W1/W2/Ws1/Ws2 are no longer pre-converted (was ~310 MB read
// + 155 MB write ~= 55-65 us of pure HBM). The GEMMs stage f32 weights
// directly and convert in-register (RNE, numerically identical).
// ---------------------------------------------------------------------------
__global__ void __launch_bounds__(256) cvt_x(const float* __restrict__ in,
                                             __hip_bfloat16* __restrict__ out,
                                             int* __restrict__ counts) {
  if (blockIdx.x == 0 && threadIdx.x < NEXP) counts[threadIdx.x] = 0;
  const size_t i = ((size_t)blockIdx.x * 256 + threadIdx.x) * 8;
  const float4 a = *(const float4*)(in + i);
  const float4 b = *(const float4*)(in + i + 4);
  union { __hip_bfloat16 h[8]; uint4 u; } p;
  p.h[0] = __float2bfloat16(a.x); p.h[1] = __float2bfloat16(a.y);
  p.h[2] = __float2bfloat16(a.z); p.h[3] = __float2bfloat16(a.w);
  p.h[4] = __float2bfloat16(b.x); p.h[5] = __float2bfloat16(b.y);
  p.h[6] = __float2bfloat16(b.z); p.h[7] = __float2bfloat16(b.w);
  *(uint4*)(out + i) = p.u;
}

__global__ void moe_zero_out(float* __restrict__ a) {
  a[(size_t)blockIdx.x * 256 + threadIdx.x] = 0.f;
}

// ---------------------------------------------------------------------------
// Round-12 core: the PROVEN r2 skeleton (128x128 tile, 4 waves, 3 LDS
// buffers, depth-2 prefetch, counted vmcnt -- never drains in main loop),
// with the B (weight) matrix staged as RAW F32 and converted to bf16 in
// register between ds_read and MFMA. A stays bf16 (xbf / h1).
// LDS per buffer: A 128x64B = 8KB (bf16) + B 128x128B = 16KB (f32) = 24KB;
// x3 buffers = 72KB -> 2 blocks/CU.
// Staging per wave per iter: 2 A-DMAs + 4 B-DMAs = 6; depth-2 -> 18
// outstanding after stage(i+2) -> vmcnt(12) waits stage(i) only.
// Swizzles (both verified bank-free on HW):
//  A (64B rows, 4 slots): store chunk c of row r at slot c^((r>>1)&3) via
//    pre-swizzled global source; read slot quad^((lr>>1)&3).  [r2: conflicts
//    6.68M -> 0]
//  B (128B rows, 8 slots): store chunk c of row r at slot c^(r&7) (lane l
//    fetches global chunk (l&7)^(l>>3) of row l>>3, linear LDS dest); read
//    slot (2*quad+cc)^(lr&7), cc=0,1.  [r5 used this scheme, refcheck'd]
// Schedule correctness (r1/r2 proven): stage(i+2) overwrites buf (i-1)%3
// whose readers all passed the trailing barrier of iter i-1; per-wave
// counted vmcnt before the leading barrier guarantees own stage(i) DMAs
// landed; the barrier publishes them to all 4 waves.
// ---------------------------------------------------------------------------
__device__ __forceinline__ void gemm_core(const char* ga0, const char* ga1,
                                          const char* const gb[4],
                                          char* sm, int niter, int tid,
                                          f32x4 acc[4][4]) {
  const int w = tid >> 6, l = tid & 63;
  const int lr = l & 15, quad = l >> 4;
  const int wr = w >> 1, wc = w & 1;
  const int swz4 = (lr >> 1) & 3;
  const int aoff = (wr * 64 + lr) * 64 + ((quad ^ swz4) * 16);
  const int s8 = lr & 7;
  const int bslot0 = ((2 * quad) ^ s8) * 16;      // f32 chunk, k = quad*8..+4
  const int bslot1 = ((2 * quad + 1) ^ s8) * 16;  // f32 chunk, k = quad*8+4..+8
  const int bbase = 8192 + (wc * 64 + lr) * 128;  // B frag j: +j*2048

  auto stage = [&](int it, int buf) {
    char* base = sm + buf * 24576;
    // A: bf16, 64B/row per K-step; wave w rows [w*16,+16) per DMA.
    async16(ga0 + it * 64, base + w * 1024);
    async16(ga1 + it * 64, base + 4096 + w * 1024);
    // B: f32, 128B/row per K-step; wave w rows [w*32,+32), 8 rows per DMA.
#pragma unroll
    for (int q = 0; q < 4; ++q)
      async16(gb[q] + it * 128, base + 8192 + w * 4096 + q * 1024);
  };

  stage(0, 0);
  stage(1, 1);
  int cur = 0, nxt = 2;
  for (int i = 0; i < niter; ++i) {
    if (i + 2 < niter) {
      stage(i + 2, nxt);                      // 18 DMAs outstanding (own)
      __builtin_amdgcn_s_waitcnt(0x0F7C);     // vmcnt(12): wait stage(i) only
    } else if (i + 1 < niter) {
      __builtin_amdgcn_s_waitcnt(0x0F76);     // vmcnt(6): stage(i+1) in flight
    } else {
      __builtin_amdgcn_s_waitcnt(0x0F70);     // vmcnt(0): last tile
    }
    __builtin_amdgcn_s_barrier();             // raw: prefetch stays in flight
    const char* rb = sm + cur * 24576;
    bf16x8 av[4], bv[4];
#pragma unroll
    for (int i2 = 0; i2 < 4; ++i2) av[i2] = *(const bf16x8*)(rb + aoff + i2 * 1024);
#pragma unroll
    for (int j = 0; j < 4; ++j) {
      const char* bp = rb + bbase + j * 2048;
      const f32x4 f0 = *(const f32x4*)(bp + bslot0);
      const f32x4 f1 = *(const f32x4*)(bp + bslot1);
      union { bf16x8 v; __hip_bfloat16 h[8]; } u;
#pragma unroll
      for (int m = 0; m < 4; ++m) {
        u.h[m] = __float2bfloat16(f0[m]);
        u.h[4 + m] = __float2bfloat16(f1[m]);
      }
      bv[j] = u.v;
    }
#pragma unroll
    for (int i2 = 0; i2 < 4; ++i2)
#pragma unroll
      for (int j = 0; j < 4; ++j)
        acc[i2][j] = __builtin_amdgcn_mfma_f32_16x16x32_bf16(av[i2], bv[j], acc[i2][j], 0, 0, 0);
    __builtin_amdgcn_s_barrier();             // all reads of buf[cur] done
    cur = (cur == 2) ? 0 : cur + 1;
    nxt = (nxt == 2) ? 0 : nxt + 1;
  }
}

// A-side staging swizzle (bf16, 64B rows): lane l stages chunk
// ((l&3)^((l>>3)&3)) of row (l>>2). Verified bank-free (r2).
__device__ __forceinline__ int stage_colb(int l) {
  return (((l & 3) ^ ((l >> 3) & 3)) * 16);
}
// B-side staging swizzle (f32, 128B rows): lane l stages chunk
// ((l&7)^(l>>3)) of row (l>>3). Verified in r5 (refcheck'd).
__device__ __forceinline__ int stage_colb8(int l) {
  return (((l & 7) ^ (l >> 3)) * 16);
}

// ---------------------------------------------------------------------------
// Gating: one wave per token. Top-2, lax.top_k tie-break (lowest index).
// ---------------------------------------------------------------------------
__global__ void __launch_bounds__(64) moe_gate(
    const float* __restrict__ x, const float* __restrict__ Wg,
    const float* __restrict__ bg, const float* __restrict__ bias,
    int* __restrict__ counts, int* __restrict__ topk_idx,
    float* __restrict__ topk_w, int* __restrict__ slot) {
  const int t = blockIdx.x, lane = threadIdx.x;
  float xv[16];
#pragma unroll
  for (int q = 0; q < 16; ++q) xv[q] = x[(size_t)t * DDIM + q * 64 + lane];
  float sc[NEXP];
#pragma unroll
  for (int e = 0; e < NEXP; ++e) {
    float s = 0.f;
#pragma unroll
    for (int q = 0; q < 16; ++q) s += xv[q] * Wg[(size_t)e * DDIM + q * 64 + lane];
#pragma unroll
    for (int o = 32; o > 0; o >>= 1) s += __shfl_xor(s, o, 64);
    sc[e] = 1.0f / (1.0f + expf(-(s + bg[e] + bias[e])));
  }
  if (lane == 0) {
    int k0 = 0;
    for (int e = 1; e < NEXP; ++e)
      if (sc[e] > sc[k0]) k0 = e;
    int k1 = (k0 == 0) ? 1 : 0;
    for (int e = 0; e < NEXP; ++e) {
      if (e == k0) continue;
      if (sc[e] > sc[k1]) k1 = e;
    }
    topk_idx[t * 2 + 0] = k0;
    topk_idx[t * 2 + 1] = k1;
    topk_w[t * 2 + 0] = sc[k0];
    topk_w[t * 2 + 1] = sc[k1];
    slot[t * 2 + 0] = atomicAdd(&counts[k0], 1);
    slot[t * 2 + 1] = atomicAdd(&counts[k1], 1);
  }
}

__global__ void moe_scan(const int* __restrict__ counts, int* __restrict__ offsets) {
  if (threadIdx.x == 0) {
    int s = 0;
    for (int e = 0; e < NEXP; ++e) { offsets[e] = s; s += counts[e]; }
    offsets[NEXP] = s;
  }
}

__global__ void moe_scatter(const int* __restrict__ topk_idx, const float* __restrict__ topk_w,
                            const int* __restrict__ slot, const int* __restrict__ offsets,
                            int* __restrict__ row_token, float* __restrict__ row_w) {
  const int t = blockIdx.x * blockDim.x + threadIdx.x;
  if (t >= NTOK) return;
#pragma unroll
  for (int k = 0; k < 2; ++k) {
    const int e = topk_idx[t * 2 + k];
    const int rg = offsets[e] + slot[t * 2 + k];
    row_token[rg] = t;
    row_w[rg] = topk_w[t * 2 + k];
  }
  row_token[2 * NTOK + t] = t;
  row_w[2 * NTOK + t] = 1.0f;
}

// ---------------------------------------------------------------------------
// Grouped GEMM1: h1[row,:] = gelu(xbf[token(row),:] @ W1[e]^T + b1[e])
// A = xbf (bf16), B = W1 (RAW F32, converted in-core).
// grid (H/128=32, NTOK/128=16, E+1).
// ---------------------------------------------------------------------------
__global__ void __launch_bounds__(256) moe_gemm1(
    const __hip_bfloat16* __restrict__ xbf, const float* __restrict__ W1,
    const float* __restrict__ b1, const float* __restrict__ Ws1,
    const float* __restrict__ bs1, const int* __restrict__ counts,
    const int* __restrict__ offsets, const int* __restrict__ row_token,
    __hip_bfloat16* __restrict__ h1) {
  __shared__ alignas(16) char sm[73728];
  const int e = blockIdx.z, mt = blockIdx.y, nt = blockIdx.x;
  const int cnt = (e < NEXP) ? counts[e] : NTOK;
  if (mt * 128 >= cnt) return;
  const int off = (e < NEXP) ? offsets[e] : 2 * NTOK;
  const float* Bw = (e < NEXP) ? (W1 + (size_t)e * HDIM * DDIM) : Ws1;
  const float* bb = (e < NEXP) ? (b1 + e * HDIM) : bs1;

  const int tid = threadIdx.x;
  const int w = tid >> 6, l = tid & 63;
  const int mrow = w * 16 + (l >> 2);   // A staging row (16 rows/DMA)
  const int colb = stage_colb(l);       // A swizzled 16B chunk
  const int colb8 = stage_colb8(l);     // B swizzled 16B chunk

  const int r0 = mt * 128 + mrow, r1 = r0 + 64;
  const int c0 = (r0 < cnt) ? r0 : (cnt - 1);
  const int c1 = (r1 < cnt) ? r1 : (cnt - 1);
  const int t0 = row_token[off + c0];
  const int t1 = row_token[off + c1];
  const char* ga0 = (const char*)xbf + (size_t)t0 * (DDIM * 2) + colb;
  const char* ga1 = (const char*)xbf + (size_t)t1 * (DDIM * 2) + colb;
  const char* gb[4];
#pragma unroll
  for (int q = 0; q < 4; ++q) {
    const int br = nt * 128 + w * 32 + q * 8 + (l >> 3);  // 8 rows/DMA
    gb[q] = (const char*)Bw + (size_t)br * (DDIM * 4) + colb8;
  }

  f32x4 acc[4][4] = {};
  gemm_core(ga0, ga1, gb, sm, DDIM / 32, tid, acc);

  const int lr = l & 15, quad = l >> 4, wr = w >> 1, wc = w & 1;
#pragma unroll
  for (int i = 0; i < 4; ++i) {
#pragma unroll
    for (int r = 0; r < 4; ++r) {
      const int rowe = mt * 128 + wr * 64 + i * 16 + quad * 4 + r;
      if (rowe >= cnt) continue;  // don't stomp next expert's rows
      const size_t orow = (size_t)(off + rowe) * HDIM;
#pragma unroll
      for (int j = 0; j < 4; ++j) {
        const int h = nt * 128 + wc * 64 + j * 16 + lr;
        const float v = acc[i][j][r] + bb[h];
        h1[orow + h] = __float2bfloat16(gelu_fast(v));
      }
    }
  }
}

// ---------------------------------------------------------------------------
// Grouped GEMM2 with split-K: out[token,:] += w(row)*(h1[row,:] @ W2[e]^T)
// (+ w*b2[e] from K-chunk 0). A = h1 (bf16), B = W2 (RAW F32).
// grid x = KSPLIT2 * (D/128) = 16; y = 16; z = E+1.
// ---------------------------------------------------------------------------
__global__ void __launch_bounds__(256) moe_gemm2(
    const __hip_bfloat16* __restrict__ h1, const float* __restrict__ W2,
    const float* __restrict__ b2, const float* __restrict__ Ws2,
    const float* __restrict__ bs2, const int* __restrict__ counts,
    const int* __restrict__ offsets, const int* __restrict__ row_token,
    const float* __restrict__ row_w, float* __restrict__ out) {
  __shared__ alignas(16) char sm[73728];
  const int e = blockIdx.z, mt = blockIdx.y;
  const int nt = blockIdx.x & (DDIM / 128 - 1);
  const int kc = blockIdx.x >> 3;  // 0..KSPLIT2-1
  const int cnt = (e < NEXP) ? counts[e] : NTOK;
  if (mt * 128 >= cnt) return;
  const int off = (e < NEXP) ? offsets[e] : 2 * NTOK;
  const float* Bw = (e < NEXP) ? (W2 + (size_t)e * DDIM * HDIM) : Ws2;
  const float* bb = (e < NEXP) ? (b2 + e * DDIM) : bs2;

  const int tid = threadIdx.x;
  const int w = tid >> 6, l = tid & 63;
  const int mrow = w * 16 + (l >> 2);
  const int colb = stage_colb(l);
  const int colb8 = stage_colb8(l);
  const int KE = HDIM / KSPLIT2;            // K elems per chunk (2048)
  const size_t kofs_a = (size_t)kc * KE * 2;  // bf16 bytes
  const size_t kofs_b = (size_t)kc * KE * 4;  // f32 bytes

  // A rows contiguous in grouped h1; rows >= cnt read the next group's valid
  // (finite) data and are discarded at the store guard.
  const char* ga0 = (const char*)h1 + (size_t)(off + mt * 128 + mrow) * (HDIM * 2) + kofs_a + colb;
  const char* ga1 = (const char*)h1 + (size_t)(off + mt * 128 + mrow + 64) * (HDIM * 2) + kofs_a + colb;
  const char* gb[4];
#pragma unroll
  for (int q = 0; q < 4; ++q) {
    const int br = nt * 128 + w * 32 + q * 8 + (l >> 3);
    gb[q] = (const char*)Bw + (size_t)br * (HDIM * 4) + kofs_b + colb8;
  }

  f32x4 acc[4][4] = {};
  gemm_core(ga0, ga1, gb, sm, KE / 32, tid, acc);

  const int lr = l & 15, quad = l >> 4, wr = w >> 1, wc = w & 1;
#pragma unroll
  for (int i = 0; i < 4; ++i) {
#pragma unroll
    for (int r = 0; r < 4; ++r) {
      const int rowe = mt * 128 + wr * 64 + i * 16 + quad * 4 + r;
      if (rowe >= cnt) continue;
      const int rg = off + rowe;
      const int tok = row_token[rg];
      const float wt = row_w[rg];
#pragma unroll
      for (int j = 0; j < 4; ++j) {
        const int d = nt * 128 + wc * 64 + j * 16 + lr;
        const float base = (kc == 0) ? bb[d] : 0.f;  // bias once per output
        atomicAdd(&out[(size_t)tok * DDIM + d], wt * (acc[i][j][r] + base));
      }
    }
  }
}

// ---------------------------------------------------------------------------
extern "C" void kernel_launch(void* const* d_in, const int* in_sizes, int n_in,
                              void* d_out, int out_size, void* d_ws, size_t ws_size,
                              hipStream_t stream) {
  (void)in_sizes; (void)n_in; (void)out_size; (void)ws_size;
  const float* x    = (const float*)d_in[0];
  const float* Wg   = (const float*)d_in[1];
  const float* bg   = (const float*)d_in[2];
  const float* bias = (const float*)d_in[3];
  const float* W1   = (const float*)d_in[4];
  const float* b1   = (const float*)d_in[5];
  const float* W2   = (const float*)d_in[6];
  const float* b2   = (const float*)d_in[7];
  const float* Ws1  = (const float*)d_in[8];
  const float* bs1  = (const float*)d_in[9];
  const float* Ws2  = (const float*)d_in[10];
  const float* bs2  = (const float*)d_in[11];
  float* out = (float*)d_out;

  char* ws = (char*)d_ws;
  size_t cur = 0;
  auto take = [&](size_t b) -> void* {
    void* p = ws + cur;
    cur += (b + 255) & ~(size_t)255;
    return p;
  };
  int* counts    = (int*)take(NEXP * 4);
  int* offsets   = (int*)take((NEXP + 1) * 4);
  int* topk_idx  = (int*)take(NTOK * 2 * 4);
  float* topk_w  = (float*)take(NTOK * 2 * 4);
  int* slot      = (int*)take(NTOK * 2 * 4);
  int* row_token = (int*)take(NROWS * 4);
  float* row_w   = (float*)take(NROWS * 4);
  __hip_bfloat16* xbf = (__hip_bfloat16*)take((size_t)NTOK * DDIM * 2);           //  4 MB
  __hip_bfloat16* h1  = (__hip_bfloat16*)take((size_t)(NROWS + 64) * HDIM * 2);   // 51 MB

  // x f32->bf16 (8 MB) + counts zeroing; weights stay f32 (converted in-core)
  cvt_x<<<(NTOK * DDIM) / 2048, 256, 0, stream>>>(x, xbf, counts);

  moe_zero_out<<<(NTOK * DDIM) / 256, 256, 0, stream>>>(out);
  moe_gate<<<NTOK, 64, 0, stream>>>(x, Wg, bg, bias, counts, topk_idx, topk_w, slot);
  moe_scan<<<1, 1, 0, stream>>>(counts, offsets);
  moe_scatter<<<NTOK / 256, 256, 0, stream>>>(topk_idx, topk_w, slot, offsets, row_token, row_w);

  dim3 g1(HDIM / 128, NTOK / 128, NEXP + 1);  // (32, 16, 9)
  moe_gemm1<<<g1, 256, 0, stream>>>(xbf, W1, b1, Ws1, bs1, counts, offsets, row_token, h1);

  dim3 g2(KSPLIT2 * (DDIM / 128), NTOK / 128, NEXP + 1);  // (16, 16, 9)
  moe_gemm2<<<g2, 256, 0, stream>>>(h1, W2, b2, Ws2, bs2, counts, offsets, row_token, row_w, out);
}

// Round 10
// 343.485 us; speedup vs baseline: 1.1152x; 1.0560x over previous
//
#include <hip/hip_runtime.h>
#include <hip/hip_bf16.h>
#include <math.h>

// Problem constants (B=2,S=1024 -> T=2048; D=1024; H=4096; E=8; top-2)
#define NTOK 2048
#define DDIM 1024
#define HDIM 4096
#define NEXP 8
#define NROWS (3 * NTOK)
#define KSPLIT2 2

typedef __bf16 bf16x8 __attribute__((ext_vector_type(8)));
typedef float f32x4 __attribute__((ext_vector_type(4)));
typedef __attribute__((address_space(1))) char as1_char;
typedef __attribute__((address_space(3))) char as3_char;

__device__ __forceinline__ void async16(const void* g, void* l) {
  __builtin_amdgcn_global_load_lds((as1_char*)g, (as3_char*)l, 16, 0, 0);
}

// Branch-free erf (A-S 7.1.26) -> exact-form gelu.
__device__ __forceinline__ float gelu_fast(float v) {
  const float x = v * 0.70710678118654752f;
  const float ax = fabsf(x);
  const float t = __builtin_amdgcn_rcpf(1.0f + 0.3275911f * ax);
  float p = 1.061405429f;
  p = p * t - 1.453152027f;
  p = p * t + 1.421413741f;
  p = p * t - 0.284496736f;
  p = p * t + 0.254829592f;
  const float y = 1.0f - p * t * __expf(-ax * ax);
  const float erfv = copysignf(y, x);
  return 0.5f * v * (1.0f + erfv);
}

__global__ void moe_zero_misc(int* counts) {
  if (threadIdx.x < NEXP) counts[threadIdx.x] = 0;
}

// ---------------------------------------------------------------------------
// "pre" mega-launch: gate (512 blocks x 4 tokens) + f32->bf16 cvt of
// x / W1 / Ws1 + out zeroing, all in ONE kernel (replaces 3-4 serial
// launches; gate overlaps the HBM-bound cvt streams).
// Blocks: gate 512 | x 1024 | W1 16384 | Ws1 2048 | zero_out 1024 = 20992.
// counts[] is zeroed by a tiny kernel BEFORE this launch (gate atomics).
// ---------------------------------------------------------------------------
__device__ __forceinline__ void cvt2048(const float* __restrict__ src,
                                        __hip_bfloat16* __restrict__ dst,
                                        int tid) {
  const size_t i = (size_t)tid * 8;
  const float4 a = *(const float4*)(src + i);
  const float4 b = *(const float4*)(src + i + 4);
  union { __hip_bfloat16 h[8]; uint4 u; } p;
  p.h[0] = __float2bfloat16(a.x); p.h[1] = __float2bfloat16(a.y);
  p.h[2] = __float2bfloat16(a.z); p.h[3] = __float2bfloat16(a.w);
  p.h[4] = __float2bfloat16(b.x); p.h[5] = __float2bfloat16(b.y);
  p.h[6] = __float2bfloat16(b.z); p.h[7] = __float2bfloat16(b.w);
  *(uint4*)(dst + i) = p.u;
}

__global__ void __launch_bounds__(256) moe_pre(
    const float* __restrict__ x, const float* __restrict__ Wg,
    const float* __restrict__ bg, const float* __restrict__ bias,
    const float* __restrict__ W1, const float* __restrict__ Ws1,
    __hip_bfloat16* __restrict__ xbf, __hip_bfloat16* __restrict__ W1bf,
    __hip_bfloat16* __restrict__ Ws1bf, float* __restrict__ out,
    int* __restrict__ counts, int* __restrict__ topk_idx,
    float* __restrict__ topk_w, int* __restrict__ slot) {
  const int b = blockIdx.x, tid = threadIdx.x;
  if (b < 512) {
    // ---- gating: wave (tid>>6) of this block handles token b*4 + wave ----
    const int t = b * 4 + (tid >> 6);
    const int lane = tid & 63;
    float xv[16];
#pragma unroll
    for (int q = 0; q < 16; ++q) xv[q] = x[(size_t)t * DDIM + q * 64 + lane];
    float sc[NEXP];
#pragma unroll
    for (int e = 0; e < NEXP; ++e) {
      float s = 0.f;
#pragma unroll
      for (int q = 0; q < 16; ++q) s += xv[q] * Wg[(size_t)e * DDIM + q * 64 + lane];
#pragma unroll
      for (int o = 32; o > 0; o >>= 1) s += __shfl_xor(s, o, 64);
      sc[e] = 1.0f / (1.0f + expf(-(s + bg[e] + bias[e])));
    }
    if (lane == 0) {
      int k0 = 0;
      for (int e = 1; e < NEXP; ++e)
        if (sc[e] > sc[k0]) k0 = e;
      int k1 = (k0 == 0) ? 1 : 0;
      for (int e = 0; e < NEXP; ++e) {
        if (e == k0) continue;
        if (sc[e] > sc[k1]) k1 = e;
      }
      topk_idx[t * 2 + 0] = k0;
      topk_idx[t * 2 + 1] = k1;
      topk_w[t * 2 + 0] = sc[k0];
      topk_w[t * 2 + 1] = sc[k1];
      slot[t * 2 + 0] = atomicAdd(&counts[k0], 1);
      slot[t * 2 + 1] = atomicAdd(&counts[k1], 1);
    }
    return;
  }
  const int cb = b - 512;
  if (cb < 1024) { cvt2048(x + (size_t)cb * 2048, xbf + (size_t)cb * 2048, tid); return; }
  if (cb < 17408) { const size_t o = (size_t)(cb - 1024) * 2048; cvt2048(W1 + o, W1bf + o, tid); return; }
  if (cb < 19456) { const size_t o = (size_t)(cb - 17408) * 2048; cvt2048(Ws1 + o, Ws1bf + o, tid); return; }
  // zero out[]: 2048 f32 per block
  const size_t o = (size_t)(cb - 19456) * 2048 + (size_t)tid * 8;
  *(float4*)(out + o) = make_float4(0.f, 0.f, 0.f, 0.f);
  *(float4*)(out + o + 4) = make_float4(0.f, 0.f, 0.f, 0.f);
}

// ---------------------------------------------------------------------------
// The PROVEN r2 GEMM core, verbatim: 128x128 tile, 4 waves, 3 LDS buffers,
// depth-2 prefetch, counted vmcnt (never drains in main loop), bank-free
// XOR swizzle (SQ_LDS_BANK_CONFLICT == 0 verified on HW). 48KB LDS ->
// 3 blocks/CU. Best measured engine across 8 rounds (143/135 us).
// Schedule correctness: stage(i+2) overwrites buf (i-1)%3 whose readers all
// passed the trailing barrier of iter i-1; per-wave vmcnt(8) before the
// leading barrier guarantees own stage(i) DMAs landed; barrier publishes.
// ---------------------------------------------------------------------------
__device__ __forceinline__ void gemm_core(const char* ga0, const char* ga1,
                                          const char* gb0, const char* gb1,
                                          char* sm, int Kbytes, int tid,
                                          f32x4 acc[4][4]) {
  const int w = tid >> 6, l = tid & 63;
  const int lr = l & 15, quad = l >> 4;
  const int wr = w >> 1, wc = w & 1;
  const int swz = (lr >> 1) & 3;
  const int aoff = (wr * 64 + lr) * 64 + ((quad ^ swz) * 16);
  const int boff = 8192 + (wc * 64 + lr) * 64 + ((quad ^ swz) * 16);
  const int niter = Kbytes >> 6;

  auto stage = [&](int it, int buf) {
    char* base = sm + buf * 16384 + w * 1024;
    const int kb = it * 64;
    async16(ga0 + kb, base);
    async16(ga1 + kb, base + 4096);
    async16(gb0 + kb, base + 8192);
    async16(gb1 + kb, base + 12288);
  };

  stage(0, 0);
  stage(1, 1);
  int cur = 0, nxt = 2;
  for (int i = 0; i < niter; ++i) {
    if (i + 2 < niter) {
      stage(i + 2, nxt);                      // 12 DMAs outstanding (own)
      __builtin_amdgcn_s_waitcnt(0x0F78);     // vmcnt(8): wait stage(i) only
    } else if (i + 1 < niter) {
      __builtin_amdgcn_s_waitcnt(0x0F74);     // vmcnt(4): stage(i+1) in flight
    } else {
      __builtin_amdgcn_s_waitcnt(0x0F70);     // vmcnt(0): last tile
    }
    __builtin_amdgcn_s_barrier();             // raw: prefetch stays in flight
    const char* rb = sm + cur * 16384;
    bf16x8 av[4], bv[4];
#pragma unroll
    for (int i2 = 0; i2 < 4; ++i2) av[i2] = *(const bf16x8*)(rb + aoff + i2 * 1024);
#pragma unroll
    for (int j = 0; j < 4; ++j) bv[j] = *(const bf16x8*)(rb + boff + j * 1024);
#pragma unroll
    for (int i2 = 0; i2 < 4; ++i2)
#pragma unroll
      for (int j = 0; j < 4; ++j)
        acc[i2][j] = __builtin_amdgcn_mfma_f32_16x16x32_bf16(av[i2], bv[j], acc[i2][j], 0, 0, 0);
    __builtin_amdgcn_s_barrier();             // all reads of buf[cur] done
    cur = (cur == 2) ? 0 : cur + 1;
    nxt = (nxt == 2) ? 0 : nxt + 1;
  }
}

// lane l stages chunk ((l&3)^((l>>3)&3)) of row (l>>2) in each 16-row DMA:
// places chunk c of row r at slot c^((r>>1)&3) with a LINEAR LDS dest.
// Verified bank-free (r2: SQ_LDS_BANK_CONFLICT 6.68M -> 0).
__device__ __forceinline__ int stage_colb(int l) {
  return (((l & 3) ^ ((l >> 3) & 3)) * 16);
}

// XCD group-swizzle: hw = (g%8) + 8*member + 64*(g/8). The 8 members of a
// group share hw%8 (same XCD under round-robin) and are dispatched within 64
// ids of each other. Members = the 8 blocks sharing one A-panel. Proven on
// HW in r7: gemm2 FETCH 300 MB -> 117 MB.
__device__ __forceinline__ void xcd_decode(int hw, int& g, int& m) {
  m = (hw >> 3) & 7;
  g = (hw & 7) + 8 * (hw >> 6);
}

__global__ void moe_scan(const int* __restrict__ counts, int* __restrict__ offsets) {
  if (threadIdx.x == 0) {
    int s = 0;
    for (int e = 0; e < NEXP; ++e) { offsets[e] = s; s += counts[e]; }
    offsets[NEXP] = s;
  }
}

__global__ void moe_scatter(const int* __restrict__ topk_idx, const float* __restrict__ topk_w,
                            const int* __restrict__ slot, const int* __restrict__ offsets,
                            int* __restrict__ row_token, float* __restrict__ row_w) {
  const int t = blockIdx.x * blockDim.x + threadIdx.x;
  if (t >= NTOK) return;
#pragma unroll
  for (int k = 0; k < 2; ++k) {
    const int e = topk_idx[t * 2 + k];
    const int rg = offsets[e] + slot[t * 2 + k];
    row_token[rg] = t;
    row_w[rg] = topk_w[t * 2 + k];
  }
  row_token[2 * NTOK + t] = t;
  row_w[2 * NTOK + t] = 1.0f;
}

// Distributed W2/Ws2 f32->bf16 conversion: gemm1's 4608 blocks each convert
// exactly 8192 elems (4096 blocks x 8192 = W2's 33.55M; 512 x 8192 = Ws2's
// 4.19M; 4608 total -- exact). Early-exit blocks convert immediately; active
// blocks convert in their epilogue. gemm2 (launched after gemm1 completes)
// sees fully-converted weights. This hides ~200 MB (~32 us) of HBM streaming
// inside gemm1's 70%-idle memory pipe instead of a serial pass.
__device__ __forceinline__ void cvt_w2_quota(int b, const float* __restrict__ W2,
                                             const float* __restrict__ Ws2,
                                             __hip_bfloat16* __restrict__ W2bf,
                                             __hip_bfloat16* __restrict__ Ws2bf,
                                             int tid) {
  const float* src;
  __hip_bfloat16* dst;
  size_t base;
  if (b < 4096) { src = W2; dst = W2bf; base = (size_t)b * 8192; }
  else          { src = Ws2; dst = Ws2bf; base = (size_t)(b - 4096) * 8192; }
#pragma unroll
  for (int k = 0; k < 8; ++k) {
    const size_t i = base + (size_t)k * 1024 + (size_t)tid * 4;
    const float4 a = *(const float4*)(src + i);
    union { __hip_bfloat16 h[4]; uint2 u; } p;
    p.h[0] = __float2bfloat16(a.x); p.h[1] = __float2bfloat16(a.y);
    p.h[2] = __float2bfloat16(a.z); p.h[3] = __float2bfloat16(a.w);
    *(uint2*)(dst + i) = p.u;
  }
}

// ---------------------------------------------------------------------------
// Grouped GEMM1: h1[row,:] = gelu(xbf[token(row),:] @ W1bf[e]^T + b1[e])
// 128x128 tiles, 1-D grid 4608, XCD-grouped (r7 decode, correctness-proven):
// member m = nt&7; group g = (nt>>3) + 4*mt + 64*e.  + distributed W2 cvt.
// ---------------------------------------------------------------------------
__global__ void __launch_bounds__(256) moe_gemm1(
    const __hip_bfloat16* __restrict__ xbf, const __hip_bfloat16* __restrict__ W1bf,
    const float* __restrict__ b1, const __hip_bfloat16* __restrict__ Ws1bf,
    const float* __restrict__ bs1, const int* __restrict__ counts,
    const int* __restrict__ offsets, const int* __restrict__ row_token,
    __hip_bfloat16* __restrict__ h1, const float* __restrict__ W2,
    const float* __restrict__ Ws2, __hip_bfloat16* __restrict__ W2bf,
    __hip_bfloat16* __restrict__ Ws2bf) {
  __shared__ alignas(16) char sm[49152];
  const int tid = threadIdx.x;
  int g, m;
  xcd_decode(blockIdx.x, g, m);
  const int nt = m + 8 * (g & 3);
  const int mt = (g >> 2) & 15;
  const int e = g >> 6;
  const int cnt = (e < NEXP) ? counts[e] : NTOK;
  if (mt * 128 >= cnt) {
    cvt_w2_quota(blockIdx.x, W2, Ws2, W2bf, Ws2bf, tid);
    return;
  }
  const int off = (e < NEXP) ? offsets[e] : 2 * NTOK;
  const __hip_bfloat16* Bw = (e < NEXP) ? (W1bf + (size_t)e * HDIM * DDIM) : Ws1bf;
  const float* bb = (e < NEXP) ? (b1 + e * HDIM) : bs1;

  const int w = tid >> 6, l = tid & 63;
  const int mrow = w * 16 + (l >> 2);
  const int colb = stage_colb(l);

  const int r0 = mt * 128 + mrow, r1 = r0 + 64;
  const int c0 = (r0 < cnt) ? r0 : (cnt - 1);
  const int c1 = (r1 < cnt) ? r1 : (cnt - 1);
  const int t0 = row_token[off + c0];
  const int t1 = row_token[off + c1];
  const char* ga0 = (const char*)xbf + (size_t)t0 * (DDIM * 2) + colb;
  const char* ga1 = (const char*)xbf + (size_t)t1 * (DDIM * 2) + colb;
  const char* gb0 = (const char*)Bw + (size_t)(nt * 128 + mrow) * (DDIM * 2) + colb;
  const char* gb1 = (const char*)Bw + (size_t)(nt * 128 + mrow + 64) * (DDIM * 2) + colb;

  f32x4 acc[4][4] = {};
  gemm_core(ga0, ga1, gb0, gb1, sm, DDIM * 2, tid, acc);

  const int lr = l & 15, quad = l >> 4, wr = w >> 1, wc = w & 1;
#pragma unroll
  for (int i = 0; i < 4; ++i) {
#pragma unroll
    for (int r = 0; r < 4; ++r) {
      const int rowe = mt * 128 + wr * 64 + i * 16 + quad * 4 + r;
      if (rowe >= cnt) continue;  // don't stomp next expert's rows
      const size_t orow = (size_t)(off + rowe) * HDIM;
#pragma unroll
      for (int j = 0; j < 4; ++j) {
        const int h = nt * 128 + wc * 64 + j * 16 + lr;
        const float v = acc[i][j][r] + bb[h];
        h1[orow + h] = __float2bfloat16(gelu_fast(v));
      }
    }
  }
  cvt_w2_quota(blockIdx.x, W2, Ws2, W2bf, Ws2bf, tid);
}

// ---------------------------------------------------------------------------
// Grouped GEMM2, split-K=2: out[token,:] += w(row)*(h1[row,:] @ W2bf[e]^T)
// (+ w*b2[e] from K-chunk 0). 128x128 tiles, 1-D grid 2304, XCD-grouped:
// member m = nt (the 8 sharers of one h1 A-panel -> one XCD);
// group g = kc + 2*mt + 32*e.  KB = HDIM*2/2 = 4096 B -> 64 iters.
// ---------------------------------------------------------------------------
__global__ void __launch_bounds__(256) moe_gemm2(
    const __hip_bfloat16* __restrict__ h1, const __hip_bfloat16* __restrict__ W2bf,
    const float* __restrict__ b2, const __hip_bfloat16* __restrict__ Ws2bf,
    const float* __restrict__ bs2, const int* __restrict__ counts,
    const int* __restrict__ offsets, const int* __restrict__ row_token,
    const float* __restrict__ row_w, float* __restrict__ out) {
  __shared__ alignas(16) char sm[49152];
  int g, m;
  xcd_decode(blockIdx.x, g, m);
  const int nt = m;            // 0..7 (D/128)
  const int kc = g & 1;        // K-chunk
  const int mt = (g >> 1) & 15;
  const int e = g >> 5;
  const int cnt = (e < NEXP) ? counts[e] : NTOK;
  if (mt * 128 >= cnt) return;
  const int off = (e < NEXP) ? offsets[e] : 2 * NTOK;
  const __hip_bfloat16* Bw = (e < NEXP) ? (W2bf + (size_t)e * DDIM * HDIM) : Ws2bf;
  const float* bb = (e < NEXP) ? (b2 + e * DDIM) : bs2;

  const int tid = threadIdx.x;
  const int w = tid >> 6, l = tid & 63;
  const int mrow = w * 16 + (l >> 2);
  const int colb = stage_colb(l);
  const int KB = (HDIM * 2) / KSPLIT2;   // 4096 bytes per chunk
  const size_t kofs = (size_t)kc * KB;

  const char* ga0 = (const char*)h1 + (size_t)(off + mt * 128 + mrow) * (HDIM * 2) + kofs + colb;
  const char* ga1 = (const char*)h1 + (size_t)(off + mt * 128 + mrow + 64) * (HDIM * 2) + kofs + colb;
  const char* gb0 = (const char*)Bw + (size_t)(nt * 128 + mrow) * (HDIM * 2) + kofs + colb;
  const char* gb1 = (const char*)Bw + (size_t)(nt * 128 + mrow + 64) * (HDIM * 2) + kofs + colb;

  f32x4 acc[4][4] = {};
  gemm_core(ga0, ga1, gb0, gb1, sm, KB, tid, acc);

  const int lr = l & 15, quad = l >> 4, wr = w >> 1, wc = w & 1;
#pragma unroll
  for (int i = 0; i < 4; ++i) {
#pragma unroll
    for (int r = 0; r < 4; ++r) {
      const int rowe = mt * 128 + wr * 64 + i * 16 + quad * 4 + r;
      if (rowe >= cnt) continue;
      const int rg = off + rowe;
      const int tok = row_token[rg];
      const float wt = row_w[rg];
#pragma unroll
      for (int j = 0; j < 4; ++j) {
        const int d = nt * 128 + wc * 64 + j * 16 + lr;
        const float base = (kc == 0) ? bb[d] : 0.f;  // bias once per output
        atomicAdd(&out[(size_t)tok * DDIM + d], wt * (acc[i][j][r] + base));
      }
    }
  }
}

// ---------------------------------------------------------------------------
extern "C" void kernel_launch(void* const* d_in, const int* in_sizes, int n_in,
                              void* d_out, int out_size, void* d_ws, size_t ws_size,
                              hipStream_t stream) {
  (void)in_sizes; (void)n_in; (void)out_size; (void)ws_size;
  const float* x    = (const float*)d_in[0];
  const float* Wg   = (const float*)d_in[1];
  const float* bg   = (const float*)d_in[2];
  const float* bias = (const float*)d_in[3];
  const float* W1   = (const float*)d_in[4];
  const float* b1   = (const float*)d_in[5];
  const float* W2   = (const float*)d_in[6];
  const float* b2   = (const float*)d_in[7];
  const float* Ws1  = (const float*)d_in[8];
  const float* bs1  = (const float*)d_in[9];
  const float* Ws2  = (const float*)d_in[10];
  const float* bs2  = (const float*)d_in[11];
  float* out = (float*)d_out;

  char* ws = (char*)d_ws;
  size_t cur = 0;
  auto take = [&](size_t b) -> void* {
    void* p = ws + cur;
    cur += (b + 255) & ~(size_t)255;
    return p;
  };
  int* counts    = (int*)take(NEXP * 4);
  int* offsets   = (int*)take((NEXP + 1) * 4);
  int* topk_idx  = (int*)take(NTOK * 2 * 4);
  float* topk_w  = (float*)take(NTOK * 2 * 4);
  int* slot      = (int*)take(NTOK * 2 * 4);
  int* row_token = (int*)take(NROWS * 4);
  float* row_w   = (float*)take(NROWS * 4);
  __hip_bfloat16* xbf   = (__hip_bfloat16*)take((size_t)NTOK * DDIM * 2);        //  4 MB
  __hip_bfloat16* W1bf  = (__hip_bfloat16*)take((size_t)NEXP * HDIM * DDIM * 2); // 67 MB
  __hip_bfloat16* W2bf  = (__hip_bfloat16*)take((size_t)NEXP * DDIM * HDIM * 2); // 67 MB
  __hip_bfloat16* Ws1bf = (__hip_bfloat16*)take((size_t)HDIM * DDIM * 2);        //  8 MB
  __hip_bfloat16* Ws2bf = (__hip_bfloat16*)take((size_t)DDIM * HDIM * 2);        //  8 MB
  __hip_bfloat16* h1    = (__hip_bfloat16*)take((size_t)(NROWS + 64) * HDIM * 2);// 51 MB

  // counts must be zero before gate atomics (gate lives inside moe_pre)
  moe_zero_misc<<<1, 64, 0, stream>>>(counts);

  // gate + cvt(x, W1, Ws1) + zero(out), one launch
  moe_pre<<<20992, 256, 0, stream>>>(x, Wg, bg, bias, W1, Ws1,
                                     xbf, W1bf, Ws1bf, out,
                                     counts, topk_idx, topk_w, slot);

  moe_scan<<<1, 1, 0, stream>>>(counts, offsets);
  moe_scatter<<<NTOK / 256, 256, 0, stream>>>(topk_idx, topk_w, slot, offsets, row_token, row_w);

  // gemm1 (XCD-grouped) + distributed W2/Ws2 conversion (every block, exact
  // 8192-elem quota; early-exit blocks convert immediately)
  moe_gemm1<<<4608, 256, 0, stream>>>(xbf, W1bf, b1, Ws1bf, bs1, counts, offsets,
                                      row_token, h1, W2, Ws2, W2bf, Ws2bf);

  // gemm2 (XCD-grouped, split-K=2) consumes the now-converted W2bf/Ws2bf
  moe_gemm2<<<2304, 256, 0, stream>>>(h1, W2bf, b2, Ws2bf, bs2, counts, offsets,
                                      row_token, row_w, out);
}